// Round 2
// baseline (1218.781 us; speedup 1.0000x reference)
//
#include <hip/hip_runtime.h>
#include <stdint.h>

#define KT 8192   // tokens
#define KD 1024   // model dim
#define KF 4096   // ffn dim
#define KE 8      // experts

typedef __bf16 bf16x8 __attribute__((ext_vector_type(8)));
typedef float  f32x4  __attribute__((ext_vector_type(4)));

__device__ __forceinline__ unsigned short f2bf(float f) {
  union { float f; uint32_t u; } v; v.f = f;
  uint32_t r = v.u + 0x7fffu + ((v.u >> 16) & 1u);   // RNE
  return (unsigned short)(r >> 16);
}
__device__ __forceinline__ float bf2f(unsigned short b) {
  union { uint32_t u; float f; } v; v.u = ((uint32_t)b) << 16;
  return v.f;
}
__device__ __forceinline__ void gl_lds16(const void* g, void* l) {
  __builtin_amdgcn_global_load_lds(
      (const __attribute__((address_space(1))) uint32_t*)g,
      (__attribute__((address_space(3))) uint32_t*)l, 16, 0, 0);
}

// ------------- convert + transpose weights: src[E][R][C] f32 -> dst[E][C][R] bf16
// Vectorized: float4 coalesced loads (16B/lane), LDS stride-66 (odd-dword: conflict-free
// column reads), dwordx4 stores (16B/lane; 2KB-strided per lane, L2 merges lines since
// the 8 waves covering each output row's 128B run in the same block).
__global__ __launch_bounds__(256) void k_transpose_cvt(const float* __restrict__ src,
                                                       unsigned short* __restrict__ dst,
                                                       int R, int C) {
  __shared__ unsigned short tile[64][66];
  const int e = blockIdx.z, r0 = blockIdx.y * 64, c0 = blockIdx.x * 64;
  const float* s = src + ((size_t)e * R + r0) * C + c0;
  const int tid = threadIdx.x;
  const int lr = tid >> 4;          // 0..15
  const int lc = (tid & 15) * 4;    // 0,4,...,60
#pragma unroll
  for (int i = 0; i < 4; ++i) {
    int r = lr + i * 16;
    float4 v = *(const float4*)(s + (size_t)r * C + lc);
    uint32_t w0 = (uint32_t)f2bf(v.x) | ((uint32_t)f2bf(v.y) << 16);
    uint32_t w1 = (uint32_t)f2bf(v.z) | ((uint32_t)f2bf(v.w) << 16);
    *(uint32_t*)&tile[r][lc]     = w0;   // byte ofs 132r+2lc: %4==0, bank 2-way = free
    *(uint32_t*)&tile[r][lc + 2] = w1;
  }
  __syncthreads();
  uint32_t* dp = (uint32_t*)(dst + ((size_t)e * C + c0) * (size_t)R + r0);
  const int Rw = R >> 1;
#pragma unroll
  for (int i = 0; i < 2; ++i) {
    int u = tid + 256 * i;
    int c = u & 63;                 // lane id within wave -> conflict-free LDS column read
    int r8 = u >> 6;                // 0..7 : which 8-row chunk of the tile
    uint32_t w[4];
#pragma unroll
    for (int j = 0; j < 4; ++j) {
      uint32_t lo = tile[r8 * 8 + 2 * j][c];
      uint32_t hi = tile[r8 * 8 + 2 * j + 1][c];
      w[j] = lo | (hi << 16);
    }
    *(uint4*)(dp + (size_t)c * Rw + r8 * 4) = *(uint4*)&w[0];
  }
}

// ---------------- router: logits, softmax, top-2, expert lists (+ x -> bf16) ----------------
__global__ __launch_bounds__(256) void k_router(const float* __restrict__ x,
                                                const float* __restrict__ Wg,
                                                const float* __restrict__ bg,
                                                unsigned short* __restrict__ xb,
                                                float* __restrict__ Psum,
                                                int* __restrict__ counts,
                                                int* __restrict__ tok_list,
                                                float* __restrict__ gate_list) {
  __shared__ float sWg[KD * 9];   // [d][e] padded stride 9 -> conflict-free
  __shared__ float sbg[8];
  __shared__ float blkP[8];
  const int tid = threadIdx.x;
  for (int i = tid; i < KD * KE; i += 256) sWg[(i >> 3) * 9 + (i & 7)] = Wg[i];
  if (tid < 8) { sbg[tid] = bg[tid]; blkP[tid] = 0.f; }
  __syncthreads();
  const int wave = tid >> 6, lane = tid & 63;
  const int t = blockIdx.x * 4 + wave;
  const float* xr = x + (size_t)t * KD;
  float acc[8];
#pragma unroll
  for (int e2 = 0; e2 < 8; ++e2) acc[e2] = 0.f;
  for (int jj = 0; jj < 16; ++jj) {
    float xv = xr[lane + jj * 64];
    xb[(size_t)t * KD + lane + jj * 64] = f2bf(xv);   // fused x -> bf16
    const float* wrow = &sWg[(lane + jj * 64) * 9];
#pragma unroll
    for (int e2 = 0; e2 < 8; ++e2) acc[e2] += xv * wrow[e2];
  }
#pragma unroll
  for (int e2 = 0; e2 < 8; ++e2) {
#pragma unroll
    for (int m = 32; m >= 1; m >>= 1) acc[e2] += __shfl_xor(acc[e2], m, 64);
  }
  if (lane == 0) {
    float lg[8], mx = -1e30f;
#pragma unroll
    for (int e2 = 0; e2 < 8; ++e2) { lg[e2] = acc[e2] + sbg[e2]; mx = fmaxf(mx, lg[e2]); }
    float p[8], ssum = 0.f;
#pragma unroll
    for (int e2 = 0; e2 < 8; ++e2) { p[e2] = __expf(lg[e2] - mx); ssum += p[e2]; }
    float inv = 1.f / ssum;
#pragma unroll
    for (int e2 = 0; e2 < 8; ++e2) { p[e2] *= inv; atomicAdd(&blkP[e2], p[e2]); }
    int i1 = 0;
#pragma unroll
    for (int e2 = 1; e2 < 8; ++e2) if (p[e2] > p[i1]) i1 = e2;
    int i2 = (i1 == 0) ? 1 : 0;
#pragma unroll
    for (int e2 = 0; e2 < 8; ++e2) if (e2 != i1 && p[e2] > p[i2]) i2 = e2;
    int pos1 = atomicAdd(&counts[i1], 1);
    tok_list[i1 * KT + pos1] = t * 2;
    gate_list[i1 * KT + pos1] = p[i1];
    int pos2 = atomicAdd(&counts[i2], 1);
    tok_list[i2 * KT + pos2] = t * 2 + 1;
    gate_list[i2 * KT + pos2] = p[i2];
  }
  __syncthreads();
  if (tid < 8) atomicAdd(&Psum[tid], blkP[tid]);
}

// ---------------- meta: offsets, row-block table, aux loss ----------------
__global__ void k_meta(const int* __restrict__ counts, const float* __restrict__ Psum,
                       int* __restrict__ offsets, int* __restrict__ rb_e,
                       int* __restrict__ rb_r0, int* __restrict__ rb_total,
                       float* __restrict__ aux_out) {
  if (threadIdx.x == 0 && blockIdx.x == 0) {
    int off = 0, nrb = 0;
    for (int e = 0; e < KE; ++e) {
      offsets[e] = off;
      int n = counts[e];
      for (int r0 = 0; r0 < n; r0 += 128) { rb_e[nrb] = e; rb_r0[nrb] = r0; ++nrb; }
      off += n;
    }
    offsets[KE] = off;
    *rb_total = nrb;
    float aux = 0.f;
    for (int e = 0; e < KE; ++e)
      aux += ((float)counts[e] / (float)(KT * 2)) * (Psum[e] / (float)KT);
    aux_out[0] = (float)KE * aux;
  }
}

// ---------------- pass A: H = silu(X@W1) * (X@W3), grouped by expert ----------------
__global__ __launch_bounds__(256, 2) void k_ffn1(
    const unsigned short* __restrict__ Xbf, const unsigned short* __restrict__ W1t,
    const unsigned short* __restrict__ W3t, const int* __restrict__ tok_list,
    const int* __restrict__ counts, const int* __restrict__ offsets,
    const int* __restrict__ rb_e, const int* __restrict__ rb_r0,
    const int* __restrict__ rb_total, unsigned short* __restrict__ H) {
  // XCD-chunked bijective swizzle: keep same-(e,n0) runs (shared W1/W3 slices) on one XCD L2
  const int gx = gridDim.x;                 // 136
  const int nwg = gx * gridDim.y;           // 4352, %8 == 0
  int lid = blockIdx.x + gx * blockIdx.y;
  lid = (lid & 7) * (nwg >> 3) + (lid >> 3);
  const int rb = lid % gx;
  if (rb >= *rb_total) return;
  const int n0 = (lid / gx) * 128;
  const int e = rb_e[rb], row0 = rb_r0[rb];
  const int ne = counts[e];
  const int g0 = offsets[e] + row0;

  __shared__ __align__(16) unsigned short sA[128 * 64];
  __shared__ __align__(16) unsigned short sB1[128 * 64];
  __shared__ __align__(16) unsigned short sB3[128 * 64];

  const int tid = threadIdx.x, wave = tid >> 6, lane = tid & 63;
  const int swz = ((lane & 7) ^ (lane >> 3)) * 8;   // XOR swizzle (row&7 == lane>>3 for our chunks)

  size_t aidx[4], bidx[4];
#pragma unroll
  for (int i = 0; i < 4; ++i) {
    int c = wave * 4 + i;
    int r = row0 + c * 8 + (lane >> 3);
    int rr = min(r, ne - 1);
    int tok = tok_list[e * KT + rr] >> 1;
    aidx[i] = (size_t)tok * KD + swz;
    int nrow = c * 8 + (lane >> 3);
    bidx[i] = ((size_t)e * KF + n0 + nrow) * KD + swz;
  }

  const int lm = lane & 15, lk = lane >> 4;
  const int waveM = (wave >> 1) * 64, waveN = (wave & 1) * 64;
  int aoff[2][4], boff[2][4];
#pragma unroll
  for (int ks = 0; ks < 2; ++ks)
#pragma unroll
    for (int t4 = 0; t4 < 4; ++t4) {
      int m = waveM + t4 * 16 + lm;
      aoff[ks][t4] = m * 64 + (((((ks << 2) | lk)) ^ (m & 7)) << 3);
      int n = waveN + t4 * 16 + lm;
      boff[ks][t4] = n * 64 + (((((ks << 2) | lk)) ^ (n & 7)) << 3);
    }

  f32x4 zero = {0.f, 0.f, 0.f, 0.f};
  f32x4 acc1[4][4], acc3[4][4];
#pragma unroll
  for (int a = 0; a < 4; ++a)
#pragma unroll
    for (int b = 0; b < 4; ++b) { acc1[a][b] = zero; acc3[a][b] = zero; }

  for (int k0 = 0; k0 < KD; k0 += 64) {
#pragma unroll
    for (int i = 0; i < 4; ++i) {
      int c = wave * 4 + i;
      gl_lds16(Xbf + aidx[i] + k0, &sA[c * 512 + lane * 8]);
      gl_lds16(W1t + bidx[i] + k0, &sB1[c * 512 + lane * 8]);
      gl_lds16(W3t + bidx[i] + k0, &sB3[c * 512 + lane * 8]);
    }
    __syncthreads();
#pragma unroll
    for (int ks = 0; ks < 2; ++ks) {
      bf16x8 af[4], bf1[4], bf3[4];
#pragma unroll
      for (int t4 = 0; t4 < 4; ++t4) {
        af[t4]  = *(const bf16x8*)&sA[aoff[ks][t4]];
        bf1[t4] = *(const bf16x8*)&sB1[boff[ks][t4]];
        bf3[t4] = *(const bf16x8*)&sB3[boff[ks][t4]];
      }
#pragma unroll
      for (int mt = 0; mt < 4; ++mt)
#pragma unroll
        for (int nt = 0; nt < 4; ++nt) {
          acc1[mt][nt] = __builtin_amdgcn_mfma_f32_16x16x32_bf16(af[mt], bf1[nt], acc1[mt][nt], 0, 0, 0);
          acc3[mt][nt] = __builtin_amdgcn_mfma_f32_16x16x32_bf16(af[mt], bf3[nt], acc3[mt][nt], 0, 0, 0);
        }
    }
    __syncthreads();
  }
#pragma unroll
  for (int mt = 0; mt < 4; ++mt)
#pragma unroll
    for (int reg = 0; reg < 4; ++reg) {
      int r = waveM + mt * 16 + lk * 4 + reg;
      if (row0 + r < ne) {
        size_t base = (size_t)(g0 + r) * KF + n0 + waveN;
#pragma unroll
        for (int nt = 0; nt < 4; ++nt) {
          float h1 = acc1[mt][nt][reg], h3 = acc3[mt][nt][reg];
          float sg = 1.f / (1.f + __expf(-h1));
          H[base + nt * 16 + lm] = f2bf(h1 * sg * h3);
        }
      }
    }
}

// ---------------- pass B: Obuf[tok*2+slot] = gate * (H @ W2), 128x256 tile ----------------
__global__ __launch_bounds__(256, 2) void k_ffn2(
    const unsigned short* __restrict__ H, const unsigned short* __restrict__ W2t,
    const int* __restrict__ tok_list, const float* __restrict__ gate_list,
    const int* __restrict__ counts, const int* __restrict__ offsets,
    const int* __restrict__ rb_e, const int* __restrict__ rb_r0,
    const int* __restrict__ rb_total, unsigned short* __restrict__ Obuf) {
  const int gx = gridDim.x;                 // 136
  const int nwg = gx * gridDim.y;           // 544, %8 == 0
  int lid = blockIdx.x + gx * blockIdx.y;
  lid = (lid & 7) * (nwg >> 3) + (lid >> 3);
  const int rb = lid % gx;
  if (rb >= *rb_total) return;
  const int n0 = (lid / gx) * 256;
  const int e = rb_e[rb], row0 = rb_r0[rb];
  const int ne = counts[e];
  const int g0 = offsets[e] + row0;
  const int nrows = ne - row0;

  __shared__ __align__(16) unsigned short sA[128 * 64];   // 16 KB
  __shared__ __align__(16) unsigned short sB[256 * 64];   // 32 KB

  const int tid = threadIdx.x, wave = tid >> 6, lane = tid & 63;
  const int swz = ((lane & 7) ^ (lane >> 3)) * 8;

  const unsigned short* Wb = W2t + (size_t)e * KD * KF;
  uint32_t aoff[4], boff[8];                // 32-bit offsets: keep VGPR+AGPR <= 256
#pragma unroll
  for (int i = 0; i < 4; ++i) {
    int c = wave * 4 + i;
    int rl = min(c * 8 + (lane >> 3), nrows - 1);
    aoff[i] = (uint32_t)(g0 + rl) * KF + swz;
  }
#pragma unroll
  for (int i = 0; i < 8; ++i) {
    int c = wave * 8 + i;
    int nrow = c * 8 + (lane >> 3);
    boff[i] = (uint32_t)(n0 + nrow) * KF + swz;
  }

  const int lm = lane & 15, lk = lane >> 4;
  const int waveM = (wave >> 1) * 64, waveN = (wave & 1) * 128;

  f32x4 zero = {0.f, 0.f, 0.f, 0.f};
  f32x4 acc[4][8];                          // 128 AGPRs
#pragma unroll
  for (int a = 0; a < 4; ++a)
#pragma unroll
    for (int b = 0; b < 8; ++b) acc[a][b] = zero;

  for (int k0 = 0; k0 < KF; k0 += 64) {
#pragma unroll
    for (int i = 0; i < 4; ++i)
      gl_lds16(H + aoff[i] + k0, &sA[(wave * 4 + i) * 512 + lane * 8]);
#pragma unroll
    for (int i = 0; i < 8; ++i)
      gl_lds16(Wb + boff[i] + k0, &sB[(wave * 8 + i) * 512 + lane * 8]);
    __syncthreads();
#pragma unroll
    for (int ks = 0; ks < 2; ++ks) {
      const int ko = ((((ks << 2) | lk) ^ (lm & 7)) << 3);   // m&7 == n&7 == lm&7 here
      bf16x8 af[4], bfr[8];
#pragma unroll
      for (int t = 0; t < 4; ++t)
        af[t] = *(const bf16x8*)&sA[(waveM + t * 16 + lm) * 64 + ko];
#pragma unroll
      for (int t = 0; t < 8; ++t)
        bfr[t] = *(const bf16x8*)&sB[(waveN + t * 16 + lm) * 64 + ko];
#pragma unroll
      for (int mt = 0; mt < 4; ++mt)
#pragma unroll
        for (int nt = 0; nt < 8; ++nt)
          acc[mt][nt] = __builtin_amdgcn_mfma_f32_16x16x32_bf16(af[mt], bfr[nt], acc[mt][nt], 0, 0, 0);
    }
    __syncthreads();
  }
#pragma unroll
  for (int mt = 0; mt < 4; ++mt)
#pragma unroll
    for (int reg = 0; reg < 4; ++reg) {
      int r = waveM + mt * 16 + lk * 4 + reg;
      if (r < nrows) {
        int li = e * KT + row0 + r;
        float gate = gate_list[li];
        int entry = tok_list[li];
        size_t base = (size_t)entry * KD + n0 + waveN;
#pragma unroll
        for (int nt = 0; nt < 8; ++nt)
          Obuf[base + nt * 16 + lm] = f2bf(acc[mt][nt][reg] * gate);
      }
    }
}

// ---------------- combine: out[t] = Obuf[2t] + Obuf[2t+1] ----------------
__global__ __launch_bounds__(256) void k_combine(const unsigned short* __restrict__ Obuf,
                                                 float* __restrict__ out) {
  int i = blockIdx.x * 256 + threadIdx.x;   // 4 elems per thread
  int t = i >> 8;
  int d = (i & 255) * 4;
  const uint32_t* r0 = (const uint32_t*)(Obuf + ((size_t)t * 2) * KD + d);
  const uint32_t* r1 = (const uint32_t*)(Obuf + ((size_t)t * 2 + 1) * KD + d);
  uint32_t a0 = r0[0], a1 = r0[1], b0 = r1[0], b1 = r1[1];
  float4 o;
  o.x = bf2f(a0 & 0xffff) + bf2f(b0 & 0xffff);
  o.y = bf2f(a0 >> 16)    + bf2f(b0 >> 16);
  o.z = bf2f(a1 & 0xffff) + bf2f(b1 & 0xffff);
  o.w = bf2f(a1 >> 16)    + bf2f(b1 >> 16);
  *(float4*)(out + (size_t)i * 4) = o;
}

extern "C" void kernel_launch(void* const* d_in, const int* in_sizes, int n_in,
                              void* d_out, int out_size, void* d_ws, size_t ws_size,
                              hipStream_t stream) {
  const float* x  = (const float*)d_in[0];
  const float* Wg = (const float*)d_in[1];
  const float* bg = (const float*)d_in[2];
  const float* W1 = (const float*)d_in[3];
  const float* W3 = (const float*)d_in[4];
  const float* W2 = (const float*)d_in[5];
  float* out = (float*)d_out;
  char* ws = (char*)d_ws;

  const size_t OFF_XBF = 0;                                    // T*D bf16
  const size_t OFF_W1T = OFF_XBF + (size_t)KT * KD * 2;
  const size_t OFF_W3T = OFF_W1T + (size_t)KE * KD * KF * 2;
  const size_t OFF_W2T = OFF_W3T + (size_t)KE * KD * KF * 2;
  const size_t OFF_H   = OFF_W2T + (size_t)KE * KD * KF * 2;   // 2T x F bf16
  const size_t OFF_OB  = OFF_H + (size_t)2 * KT * KF * 2;      // 2T x D bf16
  const size_t OFF_CNT = OFF_OB + (size_t)2 * KT * KD * 2;     // 8 ints
  const size_t OFF_PS  = OFF_CNT + 32;                         // 8 floats
  const size_t OFF_OFFS= OFF_CNT + 64;                         // 9 ints
  const size_t OFF_RBE = OFF_OFFS + 64;                        // 144 ints
  const size_t OFF_RBR = OFF_RBE + 576;
  const size_t OFF_RBT = OFF_RBR + 576;
  const size_t OFF_TOK = OFF_RBT + 64;                         // E*T ints
  const size_t OFF_GATE= OFF_TOK + (size_t)KE * KT * 4;        // E*T floats
  const size_t WS_NEED = OFF_GATE + (size_t)KE * KT * 4;
  if (ws_size < WS_NEED) return;   // workspace too small: fail loudly (untouched out)

  unsigned short* Xbf = (unsigned short*)(ws + OFF_XBF);
  unsigned short* W1t = (unsigned short*)(ws + OFF_W1T);
  unsigned short* W3t = (unsigned short*)(ws + OFF_W3T);
  unsigned short* W2t = (unsigned short*)(ws + OFF_W2T);
  unsigned short* Hb  = (unsigned short*)(ws + OFF_H);
  unsigned short* Ob  = (unsigned short*)(ws + OFF_OB);
  int*   counts   = (int*)(ws + OFF_CNT);
  float* Psum     = (float*)(ws + OFF_PS);
  int*   offsets  = (int*)(ws + OFF_OFFS);
  int*   rb_e     = (int*)(ws + OFF_RBE);
  int*   rb_r0    = (int*)(ws + OFF_RBR);
  int*   rb_total = (int*)(ws + OFF_RBT);
  int*   tok_list = (int*)(ws + OFF_TOK);
  float* gate_list= (float*)(ws + OFF_GATE);

  hipMemsetAsync(ws + OFF_CNT, 0, 64, stream);  // zero counts + Psum

  k_transpose_cvt<<<dim3(KF / 64, KD / 64, KE), 256, 0, stream>>>(W1, W1t, KD, KF);
  k_transpose_cvt<<<dim3(KF / 64, KD / 64, KE), 256, 0, stream>>>(W3, W3t, KD, KF);
  k_transpose_cvt<<<dim3(KD / 64, KF / 64, KE), 256, 0, stream>>>(W2, W2t, KF, KD);
  k_router<<<KT / 4, 256, 0, stream>>>(x, Wg, bg, Xbf, Psum, counts, tok_list, gate_list);
  k_meta<<<1, 64, 0, stream>>>(counts, Psum, offsets, rb_e, rb_r0, rb_total,
                               out + (size_t)KT * KD);
  k_ffn1<<<dim3(136, KF / 128), 256, 0, stream>>>(Xbf, W1t, W3t, tok_list, counts,
                                                  offsets, rb_e, rb_r0, rb_total, Hb);
  k_ffn2<<<dim3(136, KD / 256), 256, 0, stream>>>(Hb, W2t, tok_list, gate_list, counts,
                                                  offsets, rb_e, rb_r0, rb_total, Ob);
  k_combine<<<(KT * KD / 4) / 256, 256, 0, stream>>>(Ob, out);
}

// Round 3
// 1050.030 us; speedup vs baseline: 1.1607x; 1.1607x over previous
//
#include <hip/hip_runtime.h>
#include <stdint.h>

#define KT 8192   // tokens
#define KD 1024   // model dim
#define KF 4096   // ffn dim
#define KE 8      // experts
#define RTB 64    // router tokens per block

typedef __bf16 bf16x8 __attribute__((ext_vector_type(8)));
typedef float  f32x4  __attribute__((ext_vector_type(4)));

__device__ __forceinline__ unsigned short f2bf(float f) {
  union { float f; uint32_t u; } v; v.f = f;
  uint32_t r = v.u + 0x7fffu + ((v.u >> 16) & 1u);   // RNE
  return (unsigned short)(r >> 16);
}
__device__ __forceinline__ float bf2f(unsigned short b) {
  union { uint32_t u; float f; } v; v.u = ((uint32_t)b) << 16;
  return v.f;
}
__device__ __forceinline__ void gl_lds16(const void* g, void* l) {
  __builtin_amdgcn_global_load_lds(
      (const __attribute__((address_space(1))) uint32_t*)g,
      (__attribute__((address_space(3))) uint32_t*)l, 16, 0, 0);
}

// ------------- convert + transpose weights: src[E][R][C] f32 -> dst[E][C][R] bf16
__global__ __launch_bounds__(256) void k_transpose_cvt(const float* __restrict__ src,
                                                       unsigned short* __restrict__ dst,
                                                       int R, int C) {
  __shared__ unsigned short tile[64][66];
  const int e = blockIdx.z, r0 = blockIdx.y * 64, c0 = blockIdx.x * 64;
  const float* s = src + ((size_t)e * R + r0) * C + c0;
  const int tid = threadIdx.x;
  const int lr = tid >> 4;          // 0..15
  const int lc = (tid & 15) * 4;    // 0,4,...,60
#pragma unroll
  for (int i = 0; i < 4; ++i) {
    int r = lr + i * 16;
    float4 v = *(const float4*)(s + (size_t)r * C + lc);
    uint32_t w0 = (uint32_t)f2bf(v.x) | ((uint32_t)f2bf(v.y) << 16);
    uint32_t w1 = (uint32_t)f2bf(v.z) | ((uint32_t)f2bf(v.w) << 16);
    *(uint32_t*)&tile[r][lc]     = w0;
    *(uint32_t*)&tile[r][lc + 2] = w1;
  }
  __syncthreads();
  uint32_t* dp = (uint32_t*)(dst + ((size_t)e * C + c0) * (size_t)R + r0);
  const int Rw = R >> 1;
#pragma unroll
  for (int i = 0; i < 2; ++i) {
    int u = tid + 256 * i;
    int c = u & 63;
    int r8 = u >> 6;
    uint32_t w[4];
#pragma unroll
    for (int j = 0; j < 4; ++j) {
      uint32_t lo = tile[r8 * 8 + 2 * j][c];
      uint32_t hi = tile[r8 * 8 + 2 * j + 1][c];
      w[j] = lo | (hi << 16);
    }
    *(uint4*)(dp + (size_t)c * Rw + r8 * 4) = *(uint4*)&w[0];
  }
}

// ---------------- router: logits, softmax, top-2, expert lists (+ x -> bf16) ----------------
// Hierarchical slot assignment: LDS local ranks, 8 global atomics/block (vs 2/token),
// eliminating same-L2-line atomic serialization.
__global__ __launch_bounds__(256) void k_router(const float* __restrict__ x,
                                                const float* __restrict__ Wg,
                                                const float* __restrict__ bg,
                                                unsigned short* __restrict__ xb,
                                                float* __restrict__ Psum,
                                                int* __restrict__ counts,
                                                int* __restrict__ tok_list,
                                                float* __restrict__ gate_list) {
  __shared__ float sWg[KD * 9];   // [d][e] padded stride 9 -> conflict-free
  __shared__ float sbg[8];
  __shared__ float blkP[8];
  __shared__ int   le[2][RTB];
  __shared__ float lp[2][RTB];
  __shared__ int   lrk[2][RTB];
  __shared__ int   lcnt[8];
  __shared__ int   gbase[8];
  const int tid = threadIdx.x;
  for (int i = tid; i < KD * KE; i += 256) sWg[(i >> 3) * 9 + (i & 7)] = Wg[i];
  if (tid < 8) { sbg[tid] = bg[tid]; blkP[tid] = 0.f; lcnt[tid] = 0; }
  __syncthreads();
  const int wave = tid >> 6, lane = tid & 63;
  for (int tt = 0; tt < RTB / 4; ++tt) {
    const int tl = wave * (RTB / 4) + tt;
    const int t  = blockIdx.x * RTB + tl;
    const float* xr = x + (size_t)t * KD;
    float acc[8];
#pragma unroll
    for (int e2 = 0; e2 < 8; ++e2) acc[e2] = 0.f;
    for (int jj = 0; jj < 16; ++jj) {
      float xv = xr[lane + jj * 64];
      xb[(size_t)t * KD + lane + jj * 64] = f2bf(xv);   // fused x -> bf16
      const float* wrow = &sWg[(lane + jj * 64) * 9];
#pragma unroll
      for (int e2 = 0; e2 < 8; ++e2) acc[e2] += xv * wrow[e2];
    }
#pragma unroll
    for (int e2 = 0; e2 < 8; ++e2) {
#pragma unroll
      for (int m = 32; m >= 1; m >>= 1) acc[e2] += __shfl_xor(acc[e2], m, 64);
    }
    if (lane == 0) {
      float lg[8], mx = -1e30f;
#pragma unroll
      for (int e2 = 0; e2 < 8; ++e2) { lg[e2] = acc[e2] + sbg[e2]; mx = fmaxf(mx, lg[e2]); }
      float p[8], ssum = 0.f;
#pragma unroll
      for (int e2 = 0; e2 < 8; ++e2) { p[e2] = __expf(lg[e2] - mx); ssum += p[e2]; }
      float inv = 1.f / ssum;
#pragma unroll
      for (int e2 = 0; e2 < 8; ++e2) { p[e2] *= inv; atomicAdd(&blkP[e2], p[e2]); }
      int i1 = 0;
#pragma unroll
      for (int e2 = 1; e2 < 8; ++e2) if (p[e2] > p[i1]) i1 = e2;
      int i2 = (i1 == 0) ? 1 : 0;
#pragma unroll
      for (int e2 = 0; e2 < 8; ++e2) if (e2 != i1 && p[e2] > p[i2]) i2 = e2;
      le[0][tl] = i1; lp[0][tl] = p[i1];
      le[1][tl] = i2; lp[1][tl] = p[i2];
    }
  }
  __syncthreads();
  if (tid < RTB) {
    lrk[0][tid] = atomicAdd(&lcnt[le[0][tid]], 1);
    lrk[1][tid] = atomicAdd(&lcnt[le[1][tid]], 1);
  }
  __syncthreads();
  if (tid < 8) gbase[tid] = atomicAdd(&counts[tid], lcnt[tid]);
  __syncthreads();
  if (tid < RTB) {
    const int t2 = (blockIdx.x * RTB + tid) * 2;
    const int e1 = le[0][tid], s1 = gbase[e1] + lrk[0][tid];
    tok_list[e1 * KT + s1]  = t2;
    gate_list[e1 * KT + s1] = lp[0][tid];
    const int e2 = le[1][tid], s2 = gbase[e2] + lrk[1][tid];
    tok_list[e2 * KT + s2]  = t2 + 1;
    gate_list[e2 * KT + s2] = lp[1][tid];
  }
  if (tid < 8) atomicAdd(&Psum[tid], blkP[tid]);
}

// ---------------- meta: offsets, row-block table, aux loss ----------------
__global__ void k_meta(const int* __restrict__ counts, const float* __restrict__ Psum,
                       int* __restrict__ offsets, int* __restrict__ rb_e,
                       int* __restrict__ rb_r0, int* __restrict__ rb_total,
                       float* __restrict__ aux_out) {
  if (threadIdx.x == 0 && blockIdx.x == 0) {
    int off = 0, nrb = 0;
    for (int e = 0; e < KE; ++e) {
      offsets[e] = off;
      int n = counts[e];
      for (int r0 = 0; r0 < n; r0 += 128) { rb_e[nrb] = e; rb_r0[nrb] = r0; ++nrb; }
      off += n;
    }
    offsets[KE] = off;
    *rb_total = nrb;
    float aux = 0.f;
    for (int e = 0; e < KE; ++e)
      aux += ((float)counts[e] / (float)(KT * 2)) * (Psum[e] / (float)KT);
    aux_out[0] = (float)KE * aux;
  }
}

// ---------------- pass A: H = silu(X@W1) * (X@W3), grouped by expert ----------------
__global__ __launch_bounds__(256, 2) void k_ffn1(
    const unsigned short* __restrict__ Xbf, const unsigned short* __restrict__ W1t,
    const unsigned short* __restrict__ W3t, const int* __restrict__ tok_list,
    const int* __restrict__ counts, const int* __restrict__ offsets,
    const int* __restrict__ rb_e, const int* __restrict__ rb_r0,
    const int* __restrict__ rb_total, unsigned short* __restrict__ H) {
  const int gx = gridDim.x;                 // 136
  const int nwg = gx * gridDim.y;           // 4352, %8 == 0
  int lid = blockIdx.x + gx * blockIdx.y;
  lid = (lid & 7) * (nwg >> 3) + (lid >> 3);
  const int rb = lid % gx;
  if (rb >= *rb_total) return;
  const int n0 = (lid / gx) * 128;
  const int e = rb_e[rb], row0 = rb_r0[rb];
  const int ne = counts[e];
  const int g0 = offsets[e] + row0;

  __shared__ __align__(16) unsigned short sA[128 * 64];
  __shared__ __align__(16) unsigned short sB1[128 * 64];
  __shared__ __align__(16) unsigned short sB3[128 * 64];

  const int tid = threadIdx.x, wave = tid >> 6, lane = tid & 63;
  const int swz = ((lane & 7) ^ (lane >> 3)) * 8;

  size_t aidx[4], bidx[4];
#pragma unroll
  for (int i = 0; i < 4; ++i) {
    int c = wave * 4 + i;
    int r = row0 + c * 8 + (lane >> 3);
    int rr = min(r, ne - 1);
    int tok = tok_list[e * KT + rr] >> 1;
    aidx[i] = (size_t)tok * KD + swz;
    int nrow = c * 8 + (lane >> 3);
    bidx[i] = ((size_t)e * KF + n0 + nrow) * KD + swz;
  }

  const int lm = lane & 15, lk = lane >> 4;
  const int waveM = (wave >> 1) * 64, waveN = (wave & 1) * 64;
  int aoff[2][4], boff[2][4];
#pragma unroll
  for (int ks = 0; ks < 2; ++ks)
#pragma unroll
    for (int t4 = 0; t4 < 4; ++t4) {
      int m = waveM + t4 * 16 + lm;
      aoff[ks][t4] = m * 64 + (((((ks << 2) | lk)) ^ (m & 7)) << 3);
      int n = waveN + t4 * 16 + lm;
      boff[ks][t4] = n * 64 + (((((ks << 2) | lk)) ^ (n & 7)) << 3);
    }

  f32x4 zero = {0.f, 0.f, 0.f, 0.f};
  f32x4 acc1[4][4], acc3[4][4];
#pragma unroll
  for (int a = 0; a < 4; ++a)
#pragma unroll
    for (int b = 0; b < 4; ++b) { acc1[a][b] = zero; acc3[a][b] = zero; }

  for (int k0 = 0; k0 < KD; k0 += 64) {
#pragma unroll
    for (int i = 0; i < 4; ++i) {
      int c = wave * 4 + i;
      gl_lds16(Xbf + aidx[i] + k0, &sA[c * 512 + lane * 8]);
      gl_lds16(W1t + bidx[i] + k0, &sB1[c * 512 + lane * 8]);
      gl_lds16(W3t + bidx[i] + k0, &sB3[c * 512 + lane * 8]);
    }
    __syncthreads();
#pragma unroll
    for (int ks = 0; ks < 2; ++ks) {
      bf16x8 af[4], bf1[4], bf3[4];
#pragma unroll
      for (int t4 = 0; t4 < 4; ++t4) {
        af[t4]  = *(const bf16x8*)&sA[aoff[ks][t4]];
        bf1[t4] = *(const bf16x8*)&sB1[boff[ks][t4]];
        bf3[t4] = *(const bf16x8*)&sB3[boff[ks][t4]];
      }
#pragma unroll
      for (int mt = 0; mt < 4; ++mt)
#pragma unroll
        for (int nt = 0; nt < 4; ++nt) {
          acc1[mt][nt] = __builtin_amdgcn_mfma_f32_16x16x32_bf16(af[mt], bf1[nt], acc1[mt][nt], 0, 0, 0);
          acc3[mt][nt] = __builtin_amdgcn_mfma_f32_16x16x32_bf16(af[mt], bf3[nt], acc3[mt][nt], 0, 0, 0);
        }
    }
    __syncthreads();
  }
#pragma unroll
  for (int mt = 0; mt < 4; ++mt)
#pragma unroll
    for (int reg = 0; reg < 4; ++reg) {
      int r = waveM + mt * 16 + lk * 4 + reg;
      if (row0 + r < ne) {
        size_t base = (size_t)(g0 + r) * KF + n0 + waveN;
#pragma unroll
        for (int nt = 0; nt < 4; ++nt) {
          float h1 = acc1[mt][nt][reg], h3 = acc3[mt][nt][reg];
          float sg = 1.f / (1.f + __expf(-h1));
          H[base + nt * 16 + lm] = f2bf(h1 * sg * h3);
        }
      }
    }
}

// ---------------- pass B: Obuf[tok*2+slot] = gate * (H @ W2), 128x256 tile ----------------
__global__ __launch_bounds__(256, 2) void k_ffn2(
    const unsigned short* __restrict__ H, const unsigned short* __restrict__ W2t,
    const int* __restrict__ tok_list, const float* __restrict__ gate_list,
    const int* __restrict__ counts, const int* __restrict__ offsets,
    const int* __restrict__ rb_e, const int* __restrict__ rb_r0,
    const int* __restrict__ rb_total, unsigned short* __restrict__ Obuf) {
  const int gx = gridDim.x;                 // 136
  const int nwg = gx * gridDim.y;           // 544, %8 == 0
  int lid = blockIdx.x + gx * blockIdx.y;
  lid = (lid & 7) * (nwg >> 3) + (lid >> 3);
  const int rb = lid % gx;
  if (rb >= *rb_total) return;
  const int n0 = (lid / gx) * 256;
  const int e = rb_e[rb], row0 = rb_r0[rb];
  const int ne = counts[e];
  const int g0 = offsets[e] + row0;
  const int nrows = ne - row0;

  __shared__ __align__(16) unsigned short sA[128 * 64];   // 16 KB
  __shared__ __align__(16) unsigned short sB[256 * 64];   // 32 KB

  const int tid = threadIdx.x, wave = tid >> 6, lane = tid & 63;
  const int swz = ((lane & 7) ^ (lane >> 3)) * 8;

  const unsigned short* Wb = W2t + (size_t)e * KD * KF;
  uint32_t aoff[4], boff[8];
#pragma unroll
  for (int i = 0; i < 4; ++i) {
    int c = wave * 4 + i;
    int rl = min(c * 8 + (lane >> 3), nrows - 1);
    aoff[i] = (uint32_t)(g0 + rl) * KF + swz;
  }
#pragma unroll
  for (int i = 0; i < 8; ++i) {
    int c = wave * 8 + i;
    int nrow = c * 8 + (lane >> 3);
    boff[i] = (uint32_t)(n0 + nrow) * KF + swz;
  }

  const int lm = lane & 15, lk = lane >> 4;
  const int waveM = (wave >> 1) * 64, waveN = (wave & 1) * 128;

  f32x4 zero = {0.f, 0.f, 0.f, 0.f};
  f32x4 acc[4][8];                          // 128 AGPRs
#pragma unroll
  for (int a = 0; a < 4; ++a)
#pragma unroll
    for (int b = 0; b < 8; ++b) acc[a][b] = zero;

  for (int k0 = 0; k0 < KF; k0 += 64) {
#pragma unroll
    for (int i = 0; i < 4; ++i)
      gl_lds16(H + aoff[i] + k0, &sA[(wave * 4 + i) * 512 + lane * 8]);
#pragma unroll
    for (int i = 0; i < 8; ++i)
      gl_lds16(Wb + boff[i] + k0, &sB[(wave * 8 + i) * 512 + lane * 8]);
    __syncthreads();
#pragma unroll
    for (int ks = 0; ks < 2; ++ks) {
      const int ko = ((((ks << 2) | lk) ^ (lm & 7)) << 3);
      bf16x8 af[4], bfr[8];
#pragma unroll
      for (int t = 0; t < 4; ++t)
        af[t] = *(const bf16x8*)&sA[(waveM + t * 16 + lm) * 64 + ko];
#pragma unroll
      for (int t = 0; t < 8; ++t)
        bfr[t] = *(const bf16x8*)&sB[(waveN + t * 16 + lm) * 64 + ko];
#pragma unroll
      for (int mt = 0; mt < 4; ++mt)
#pragma unroll
        for (int nt = 0; nt < 8; ++nt)
          acc[mt][nt] = __builtin_amdgcn_mfma_f32_16x16x32_bf16(af[mt], bfr[nt], acc[mt][nt], 0, 0, 0);
    }
    __syncthreads();
  }
#pragma unroll
  for (int mt = 0; mt < 4; ++mt)
#pragma unroll
    for (int reg = 0; reg < 4; ++reg) {
      int r = waveM + mt * 16 + lk * 4 + reg;
      if (r < nrows) {
        int li = e * KT + row0 + r;
        float gate = gate_list[li];
        int entry = tok_list[li];
        size_t base = (size_t)entry * KD + n0 + waveN;
#pragma unroll
        for (int nt = 0; nt < 8; ++nt)
          Obuf[base + nt * 16 + lm] = f2bf(acc[mt][nt][reg] * gate);
      }
    }
}

// ---------------- combine: out[t] = Obuf[2t] + Obuf[2t+1] ----------------
__global__ __launch_bounds__(256) void k_combine(const unsigned short* __restrict__ Obuf,
                                                 float* __restrict__ out) {
  int i = blockIdx.x * 256 + threadIdx.x;   // 4 elems per thread
  int t = i >> 8;
  int d = (i & 255) * 4;
  const uint32_t* r0 = (const uint32_t*)(Obuf + ((size_t)t * 2) * KD + d);
  const uint32_t* r1 = (const uint32_t*)(Obuf + ((size_t)t * 2 + 1) * KD + d);
  uint32_t a0 = r0[0], a1 = r0[1], b0 = r1[0], b1 = r1[1];
  float4 o;
  o.x = bf2f(a0 & 0xffff) + bf2f(b0 & 0xffff);
  o.y = bf2f(a0 >> 16)    + bf2f(b0 >> 16);
  o.z = bf2f(a1 & 0xffff) + bf2f(b1 & 0xffff);
  o.w = bf2f(a1 >> 16)    + bf2f(b1 >> 16);
  *(float4*)(out + (size_t)i * 4) = o;
}

extern "C" void kernel_launch(void* const* d_in, const int* in_sizes, int n_in,
                              void* d_out, int out_size, void* d_ws, size_t ws_size,
                              hipStream_t stream) {
  const float* x  = (const float*)d_in[0];
  const float* Wg = (const float*)d_in[1];
  const float* bg = (const float*)d_in[2];
  const float* W1 = (const float*)d_in[3];
  const float* W3 = (const float*)d_in[4];
  const float* W2 = (const float*)d_in[5];
  float* out = (float*)d_out;
  char* ws = (char*)d_ws;

  const size_t OFF_XBF = 0;                                    // T*D bf16
  const size_t OFF_W1T = OFF_XBF + (size_t)KT * KD * 2;
  const size_t OFF_W3T = OFF_W1T + (size_t)KE * KD * KF * 2;
  const size_t OFF_W2T = OFF_W3T + (size_t)KE * KD * KF * 2;
  const size_t OFF_H   = OFF_W2T + (size_t)KE * KD * KF * 2;   // 2T x F bf16
  const size_t OFF_OB  = OFF_H + (size_t)2 * KT * KF * 2;      // 2T x D bf16
  const size_t OFF_CNT = OFF_OB + (size_t)2 * KT * KD * 2;     // 8 ints (own 64B line)
  const size_t OFF_PS  = OFF_CNT + 64;                         // 8 floats (own 64B line)
  const size_t OFF_OFFS= OFF_CNT + 128;                        // 9 ints
  const size_t OFF_RBE = OFF_OFFS + 64;                        // 144 ints
  const size_t OFF_RBR = OFF_RBE + 576;
  const size_t OFF_RBT = OFF_RBR + 576;
  const size_t OFF_TOK = OFF_RBT + 64;                         // E*T ints
  const size_t OFF_GATE= OFF_TOK + (size_t)KE * KT * 4;        // E*T floats
  const size_t WS_NEED = OFF_GATE + (size_t)KE * KT * 4;
  if (ws_size < WS_NEED) return;   // workspace too small: fail loudly (untouched out)

  unsigned short* Xbf = (unsigned short*)(ws + OFF_XBF);
  unsigned short* W1t = (unsigned short*)(ws + OFF_W1T);
  unsigned short* W3t = (unsigned short*)(ws + OFF_W3T);
  unsigned short* W2t = (unsigned short*)(ws + OFF_W2T);
  unsigned short* Hb  = (unsigned short*)(ws + OFF_H);
  unsigned short* Ob  = (unsigned short*)(ws + OFF_OB);
  int*   counts   = (int*)(ws + OFF_CNT);
  float* Psum     = (float*)(ws + OFF_PS);
  int*   offsets  = (int*)(ws + OFF_OFFS);
  int*   rb_e     = (int*)(ws + OFF_RBE);
  int*   rb_r0    = (int*)(ws + OFF_RBR);
  int*   rb_total = (int*)(ws + OFF_RBT);
  int*   tok_list = (int*)(ws + OFF_TOK);
  float* gate_list= (float*)(ws + OFF_GATE);

  hipMemsetAsync(ws + OFF_CNT, 0, 128, stream);  // zero counts + Psum

  k_transpose_cvt<<<dim3(KF / 64, KD / 64, KE), 256, 0, stream>>>(W1, W1t, KD, KF);
  k_transpose_cvt<<<dim3(KF / 64, KD / 64, KE), 256, 0, stream>>>(W3, W3t, KD, KF);
  k_transpose_cvt<<<dim3(KD / 64, KF / 64, KE), 256, 0, stream>>>(W2, W2t, KF, KD);
  k_router<<<KT / RTB, 256, 0, stream>>>(x, Wg, bg, Xbf, Psum, counts, tok_list, gate_list);
  k_meta<<<1, 64, 0, stream>>>(counts, Psum, offsets, rb_e, rb_r0, rb_total,
                               out + (size_t)KT * KD);
  k_ffn1<<<dim3(136, KF / 128), 256, 0, stream>>>(Xbf, W1t, W3t, tok_list, counts,
                                                  offsets, rb_e, rb_r0, rb_total, Hb);
  k_ffn2<<<dim3(136, KD / 256), 256, 0, stream>>>(Hb, W2t, tok_list, gate_list, counts,
                                                  offsets, rb_e, rb_r0, rb_total, Ob);
  k_combine<<<(KT * KD / 4) / 256, 256, 0, stream>>>(Ob, out);
}